// Round 11
// baseline (166.348 us; speedup 1.0000x reference)
//
#include <hip/hip_runtime.h>
#include <math.h>

// NeuralSplineCoupling: y[:, :3] = RQS(x[:, :3]; params = MLP([x[:,3:], c]))
//                       y[:, 3:] = x[:, 3:],  log_det = sum over 3 dims
// N = 500000, X_DIM=6, C_DIM=4, HID=128, KNOTS=16, SPLINE_DIM=47, OUT_DIM=141
//
// Round 23: OCCUPANCY is the lever. Measured map: 8 waves/CU -> 88-89us
// (r12/r22), 16 waves/CU -> 76-80us (r13/r19), independent of per-wave
// traffic (32x32 halved LDS reads+insts, still lost at 8 waves) and barrier
// count. Latency-bound; no pipe saturated. The 77.8KB blob caps blocks at 2
// (16 waves). r23: stage ONLY W1+W2 (40KB) in LDS; read W3 fragments (36KB,
// L2/L3-resident chip-wide, coalesced 1KB/wave) directly from Wall in P3.
// shp16 (38.9KB) overlays W1W2s after barrier A. Block LDS = 42496 B ->
// 3 blocks/CU -> 24 waves/CU, same r13-measured per-thread body (16x16,
// 1-set/wave). W3 L2 traffic 1.125GB (~33us aggregate) overlaps LDS+MFMA.
// LDS: [W1s 8192 | W2s 32768] overlaid by shp16 128x304=38912 | shld 1536.

#define TILE 128
#define NT   512
#define HID  128
#define OUTD 141
#define SRS  152     // halves per sample in shp16 (304 B rows)
#define BND  5.0f
#define T1   0.5413248546f   // ln(e-1): softplus(T1) = 1

typedef __bf16 bf16;
typedef _Float16 f16;
typedef __attribute__((ext_vector_type(8))) __bf16 bf16x8;
typedef __attribute__((ext_vector_type(8))) _Float16 f16x8;
typedef __attribute__((ext_vector_type(4))) _Float16 f16x4;
typedef __attribute__((ext_vector_type(2))) _Float16 f16x2;
typedef __attribute__((ext_vector_type(4))) float f32x4;

// fragment-index bases in the packed weight blob (fragment = 64 lanes x 16 B)
#define W3BASE 0         // 9 t3 x 4 kc = 36 tiles -> frags [0, 2304)
#define W1BASE 2304      // 8 tiles               -> frags [2304, 2816)
#define W2BASE 2816      // 8 m-tiles x 4 kc      -> frags [2816, 4864)
#define NFRAG  4864      // 77824 bytes total
#define B3P_OFF (NFRAG * 16)   // byte offset of b3p in d_ws

// LDS layout (per block): wlds [0, 40960) = W1s(512 frags) + W2s(2048 frags);
// shp16 [0, 38912) overlays wlds AFTER barrier A; shld [40960, 42496).
#define NSTAGE    2560        // frags staged (W1+W2)
#define SHLD_OFF  40960
#define SMEM_BYTES 42496      // -> 3 blocks/CU (163840/42496 = 3.85)

// One thread per 8-elem A-fragment (W^T in A-layout: A[m=lane&15][k=lq*8+j]).
// k-permutation for W2/W3: feat = (kc*2+(j>>2))*16 + lq*4 + (j&3)  (f mapping,
// matches the in-lane D->B repack of the transposed chain — verified r11/r13).
__global__ void nsc_prepack(const float* __restrict__ W1, const float* __restrict__ W2,
                            const float* __restrict__ W3, const float* __restrict__ b3,
                            bf16* __restrict__ Wall, float* __restrict__ b3p) {
    int f = blockIdx.x * 256 + threadIdx.x;
    int lane = f & 63, lm = lane & 15, lq = lane >> 4;
    if (f < W1BASE) {                                // W3^T frags
        int tk = f >> 6, t3 = tk >> 2, kc = tk & 3;
        int col = t3 * 16 + lm;
        bf16x8 pk;
        #pragma unroll
        for (int j = 0; j < 8; ++j) {
            int feat = ((kc * 2 + (j >> 2)) << 4) + (lq << 2) + (j & 3);
            pk[j] = (col < OUTD) ? (bf16)W3[feat * OUTD + col] : (bf16)0.f;
        }
        *(bf16x8*)&Wall[(size_t)f * 8] = pk;
    } else if (f < W2BASE) {                         // W1^T frags (identity k, 7 feats)
        int t = (f - W1BASE) >> 6;
        int m = t * 16 + lm;
        bf16x8 pk;
        #pragma unroll
        for (int j = 0; j < 8; ++j) {
            int k = lq * 8 + j;
            pk[j] = (k < 7) ? (bf16)W1[k * HID + m] : (bf16)0.f;
        }
        *(bf16x8*)&Wall[(size_t)f * 8] = pk;
    } else if (f < NFRAG) {                          // W2^T frags
        int tk = (f - W2BASE) >> 6, t2 = tk >> 2, kc = tk & 3;
        int m = t2 * 16 + lm;
        bf16x8 pk;
        #pragma unroll
        for (int j = 0; j < 8; ++j) {
            int feat = ((kc * 2 + (j >> 2)) << 4) + (lq << 2) + (j & 3);
            pk[j] = (bf16)W2[feat * HID + m];
        }
        *(bf16x8*)&Wall[(size_t)f * 8] = pk;
    } else if (f < NFRAG + 144) {                    // b3 padded to 144
        int i = f - NFRAG;
        b3p[i] = (i < OUTD) ? b3[i] : 0.f;
    }
}

__global__ __launch_bounds__(NT, 6) void nsc_main(
    const float* __restrict__ x, const float* __restrict__ c,
    const bf16* __restrict__ Wall, const float* __restrict__ b1,
    const float* __restrict__ b2, const float* __restrict__ b3p,
    float* __restrict__ out_y, float* __restrict__ out_ld, int N)
{
    __shared__ __align__(16) char smem[SMEM_BYTES];
    bf16*  wlds  = (bf16*)smem;                 // W1s+W2s (2560 frags)
    f16*   shp16 = (f16*)smem;                  // [128][SRS], overlays wlds after BARRIER A
    float* shld  = (float*)(smem + SHLD_OFF);   // [128][3]

    const int tid  = threadIdx.x;
    const int g0   = blockIdx.x * TILE;
    const int lane = tid & 63;
    const int wv   = tid >> 6;        // 0..7: wave owns samples wv*16 .. wv*16+15
    const int lm   = lane & 15;
    const int lq   = lane >> 4;
    const int sbase = wv * 16;

    // ---- Input loads first (overlap with staging) ----
    float vin[8];
    #pragma unroll
    for (int j = 0; j < 8; ++j) vin[j] = 0.f;
    {
        int g = g0 + sbase + lm;
        if (lq == 0 && g < N) {
            vin[0] = x[g * 6 + 3]; vin[1] = x[g * 6 + 4];
            vin[2] = x[g * 6 + 5];
            vin[3] = c[g * 4];     vin[4] = c[g * 4 + 1];
            vin[5] = c[g * 4 + 2]; vin[6] = c[g * 4 + 3];
        }
    }

    // ---- Stage W1+W2 (40960 B): 5 x (dwordx4 load + b128 LDS store) ----
    {
        const float4* src = (const float4*)(Wall + (size_t)W1BASE * 8);
        float4* dst = (float4*)smem;
        #pragma unroll
        for (int j = 0; j < 5; ++j) {
            int idx = tid + j * NT;           // 0..2559
            dst[idx] = src[idx];
        }
    }
    __syncthreads();   // staging complete

    // ---- Build B1 input fragment (B[k=lq*8+j][n=sample lm]) ----
    bf16x8 inb;
    {
        bf16x8 t;
        #pragma unroll
        for (int j = 0; j < 8; ++j) t[j] = (bf16)vin[j];
        inb = t;
    }

    // ---- Phase 1: h1^T = W1^T @ in^T + b1 (W1s at LDS frags [0,512)) ----
    f32x4 acc1[8];
    {
        #pragma unroll
        for (int t = 0; t < 8; ++t)
            acc1[t] = *(const f32x4*)&b1[t * 16 + lq * 4];
        #pragma unroll
        for (int t = 0; t < 8; ++t) {
            bf16x8 wf = *(const bf16x8*)&wlds[(size_t)((t * 64 + lane)) * 8];
            acc1[t] = __builtin_amdgcn_mfma_f32_16x16x32_bf16(wf, inb, acc1[t], 0, 0, 0);
        }
    }
    // in-lane D->B repack: B2 slot (kc,j) <- relu(D1[t = kc*2+(j>>2)].r[j&3])
    bf16x8 h1B[4];
    #pragma unroll
    for (int kc = 0; kc < 4; ++kc) {
        bf16x8 hb;
        #pragma unroll
        for (int j = 0; j < 8; ++j)
            hb[j] = (bf16)fmaxf(acc1[kc * 2 + (j >> 2)][j & 3], 0.f);
        h1B[kc] = hb;
    }

    // ---- Phase 2: h2^T = W2^T @ h1^T + b2 (W2s at LDS frags [512,2560)) ----
    bf16x8 h2B[4];
    #pragma unroll
    for (int tp = 0; tp < 4; ++tp) {
        f32x4 acc[2];
        #pragma unroll
        for (int dt = 0; dt < 2; ++dt)
            acc[dt] = *(const f32x4*)&b2[(tp * 2 + dt) * 16 + lq * 4];
        #pragma unroll
        for (int kc = 0; kc < 4; ++kc)
            #pragma unroll
            for (int dt = 0; dt < 2; ++dt) {
                bf16x8 wf = *(const bf16x8*)&wlds[(size_t)((512 + ((tp * 2 + dt) * 4 + kc) * 64 + lane)) * 8];
                acc[dt] = __builtin_amdgcn_mfma_f32_16x16x32_bf16(wf, h1B[kc], acc[dt], 0, 0, 0);
            }
        bf16x8 hb;
        #pragma unroll
        for (int j = 0; j < 8; ++j)
            hb[j] = (bf16)fmaxf(acc[j >> 2][j & 3], 0.f);
        h2B[tp] = hb;      // kc-group of next GEMM == tp (f mapping)
    }
    __syncthreads();   // BARRIER A: all waves done reading W1s/W2s -> shp16 free

    // ---- Phase 3: p^T = W3^T @ h2^T + b3 — W3 frags DIRECT FROM L2 ----
    #pragma unroll
    for (int t3 = 0; t3 < 9; ++t3) {
        f32x4 acc = *(const f32x4*)&b3p[t3 * 16 + lq * 4];
        #pragma unroll
        for (int kc = 0; kc < 4; ++kc) {
            bf16x8 wf = *(const bf16x8*)&Wall[(size_t)((t3 * 4 + kc) * 64 + lane) * 8];
            acc = __builtin_amdgcn_mfma_f32_16x16x32_bf16(wf, h2B[kc], acc, 0, 0, 0);
        }
        {
            int s = sbase + lm;
            f16x4 pk = (f16x4){(f16)acc[0], (f16)acc[1],
                               (f16)acc[2], (f16)acc[3]};
            int off = t3 * 16 + lq * 4;   // off = col; 8B-aligned b64 store
            if (t3 < 8) {
                *(f16x4*)&shp16[s * SRS + off] = pk;
            } else {
                if (lq < 3) *(f16x4*)&shp16[s * SRS + off] = pk;
                else        shp16[s * SRS + 140] = pk[0];   // col 140 only
            }
        }
    }
    __syncthreads();   // BARRIER B: scatters visible to all waves

    // ---- Phase 4: spline; 6 groups over 8 waves (waves 0..5), d uniform ----
    if (wv < 6) {
        const int grp = wv;
        const int d = grp >> 1;
        const int s = ((grp & 1) << 6) + lane;
        const int g = g0 + s;
        if (g < N) {
            const f16* pr = &shp16[s * SRS];
            float w_[16], h_[16], dl[15];
            if (d == 0) {               // p[0..46]
                f16x8 A0 = *(const f16x8*)&pr[0],  A1 = *(const f16x8*)&pr[8];
                f16x8 A2 = *(const f16x8*)&pr[16], A3 = *(const f16x8*)&pr[24];
                f16x8 A4 = *(const f16x8*)&pr[32], A5 = *(const f16x8*)&pr[40];
                #pragma unroll
                for (int i = 0; i < 8; ++i) {
                    w_[i] = (float)A0[i]; w_[8 + i] = (float)A1[i];
                    h_[i] = (float)A2[i]; h_[8 + i] = (float)A3[i];
                    dl[i] = (float)A4[i];
                }
                #pragma unroll
                for (int i = 0; i < 7; ++i) dl[8 + i] = (float)A5[i];
            } else if (d == 1) {        // p[47..93]
                float a47 = (float)pr[47];
                f16x8 A0 = *(const f16x8*)&pr[48], A1 = *(const f16x8*)&pr[56];
                f16x8 A2 = *(const f16x8*)&pr[64], A3 = *(const f16x8*)&pr[72];
                f16x8 A4 = *(const f16x8*)&pr[80], A5 = *(const f16x8*)&pr[88];
                w_[0] = a47;
                #pragma unroll
                for (int i = 0; i < 8; ++i) w_[1 + i] = (float)A0[i];
                #pragma unroll
                for (int i = 0; i < 7; ++i) w_[9 + i] = (float)A1[i];
                h_[0] = (float)A1[7];
                #pragma unroll
                for (int i = 0; i < 8; ++i) h_[1 + i] = (float)A2[i];
                #pragma unroll
                for (int i = 0; i < 7; ++i) h_[9 + i] = (float)A3[i];
                dl[0] = (float)A3[7];
                #pragma unroll
                for (int i = 0; i < 8; ++i) dl[1 + i] = (float)A4[i];
                #pragma unroll
                for (int i = 0; i < 6; ++i) dl[9 + i] = (float)A5[i];
            } else {                    // p[94..140]
                f16x2 B  = *(const f16x2*)&pr[94];
                f16x8 C0 = *(const f16x8*)&pr[96],  C1 = *(const f16x8*)&pr[104];
                f16x8 C2 = *(const f16x8*)&pr[112], C3 = *(const f16x8*)&pr[120];
                f16x8 C4 = *(const f16x8*)&pr[128], E  = *(const f16x8*)&pr[136];
                w_[0] = (float)B[0]; w_[1] = (float)B[1];
                #pragma unroll
                for (int i = 0; i < 8; ++i) w_[2 + i] = (float)C0[i];
                #pragma unroll
                for (int i = 0; i < 6; ++i) w_[10 + i] = (float)C1[i];
                h_[0] = (float)C1[6]; h_[1] = (float)C1[7];
                #pragma unroll
                for (int i = 0; i < 8; ++i) h_[2 + i] = (float)C2[i];
                #pragma unroll
                for (int i = 0; i < 6; ++i) h_[10 + i] = (float)C3[i];
                dl[0] = (float)C3[6]; dl[1] = (float)C3[7];
                #pragma unroll
                for (int i = 0; i < 8; ++i) dl[2 + i] = (float)C4[i];
                #pragma unroll
                for (int i = 0; i < 5; ++i) dl[10 + i] = (float)E[i];
            }

            // softmax without max-subtract: logits are O(1)
            float sw = 0.f, sh = 0.f;
            #pragma unroll
            for (int i = 0; i < 16; ++i) { w_[i] = __expf(w_[i]); sw += w_[i]; }
            #pragma unroll
            for (int i = 0; i < 16; ++i) { h_[i] = __expf(h_[i]); sh += h_[i]; }
            float cwn = 10.f * __builtin_amdgcn_rcpf(sw);
            float chn = 10.f * __builtin_amdgcn_rcpf(sh);
            #pragma unroll
            for (int i = 0; i < 16; ++i) { w_[i] *= cwn; h_[i] *= chn; }

            float xv = x[g * 6 + d];
            bool oob = (xv <= -BND) || (xv >= BND);
            float xm = oob ? -BND : xv;

            // bin scan; softplus deferred to the 2 selected derivs
            float cumx = -BND + w_[0], cumy = -BND + h_[0];
            float xk_b = -BND, yk_b = -BND;
            float wk = w_[0], hk = h_[0];
            float d0l = T1, d1l = dl[0];
            #pragma unroll
            for (int i = 1; i < 16; ++i) {
                bool ge = (xm >= cumx);
                if (ge) {
                    xk_b = cumx; yk_b = cumy;
                    wk = w_[i]; hk = h_[i];
                    d0l = dl[i - 1];
                    d1l = (i < 15) ? dl[i] : T1;
                }
                cumx += w_[i]; cumy += h_[i];
            }
            float d0 = (d0l > 15.f) ? d0l : __logf(1.f + __expf(d0l));
            float d1 = (d1l > 15.f) ? d1l : __logf(1.f + __expf(d1l));

            float rwk = __builtin_amdgcn_rcpf(wk);
            float sk = hk * rwk;
            float relx = (xm - xk_b) * rwk;
            relx = fminf(fmaxf(relx, 0.f), 1.f);
            float r1 = relx * (1.f - relx);
            float den = sk + (d1 + d0 - 2.f * sk) * r1;
            float iden = __builtin_amdgcn_rcpf(den);
            float num = hk * (sk * relx * relx + d0 * r1);
            float y = yk_b + num * iden;
            float omr = 1.f - relx;
            float arg = d1 * relx * relx + 2.f * sk * r1 + d0 * omr * omr;
            float ratio = sk * iden;
            float ld = __logf(ratio * ratio * arg);   // 2log(sk)+log(arg)-2log(den)
            if (oob) { y = xv; ld = 0.f; }

            out_y[g * 6 + d] = y;
            out_y[g * 6 + 3 + d] = x[g * 6 + 3 + d];  // upper pass-through (fp32)
            shld[s * 3 + d] = ld;
        }
    }
    __syncthreads();   // BARRIER C

    // ---- Phase 5: reduce log-det over the 3 dims ----
    if (tid < TILE) {
        int g = g0 + tid;
        if (g < N)
            out_ld[g] = shld[tid * 3] + shld[tid * 3 + 1] + shld[tid * 3 + 2];
    }
}

extern "C" void kernel_launch(void* const* d_in, const int* in_sizes, int n_in,
                              void* d_out, int out_size, void* d_ws, size_t ws_size,
                              hipStream_t stream) {
    const float* x  = (const float*)d_in[0];
    const float* c  = (const float*)d_in[1];
    const float* W1 = (const float*)d_in[2];
    const float* b1 = (const float*)d_in[3];
    const float* W2 = (const float*)d_in[4];
    const float* b2 = (const float*)d_in[5];
    const float* W3 = (const float*)d_in[6];
    const float* b3 = (const float*)d_in[7];

    const int N = in_sizes[0] / 6;              // 500000
    float* out_y  = (float*)d_out;
    float* out_ld = (float*)d_out + (size_t)N * 6;

    bf16*  Wall = (bf16*)d_ws;                          // 77824 B blob
    float* b3p  = (float*)((char*)d_ws + B3P_OFF);      // 576 B

    int nthreads = NFRAG + 144;                 // 5008
    nsc_prepack<<<(nthreads + 255) / 256, 256, 0, stream>>>(W1, W2, W3, b3,
                                                            Wall, b3p);

    int nblocks = (N + TILE - 1) / TILE;        // 3907
    nsc_main<<<nblocks, NT, 0, stream>>>(x, c, Wall, b1, b2, b3p,
                                         out_y, out_ld, N);
}

// Round 13
// 133.668 us; speedup vs baseline: 1.2445x; 1.2445x over previous
//
#include <hip/hip_runtime.h>
#include <math.h>

// NeuralSplineCoupling: y[:, :3] = RQS(x[:, :3]; params = MLP([x[:,3:], c]))
//                       y[:, 3:] = x[:, 3:],  log_det = sum over 3 dims
// N = 500000, X_DIM=6, C_DIM=4, HID=128, KNOTS=16, SPLINE_DIM=47, OUT_DIM=141
//
// Round 25 == Round 24 with the compile error fixed (malformed declaration in
// the d==2 spline branch; experiment never ran).
// FRAG-SHARING at 16 waves/CU (the untried combination).
// Measured map: r13 (16 waves, 1 set/wave, blob-in-LDS) = 76us BEST;
// r12 (8 waves, 2 sets/wave) = 89; r22 (8 waves, 32x32) = 88; r23 (24 waves,
// W3-from-L2) = 98 (global latency in P3 chain — occupancy alone is NOT the
// lever). r12 proved one ds_read_b128 can feed 2 MFMAs (halves LDS fragment
// traffic) but ran at 8 waves. This kernel combines both: 2 sets/wave AND
// 16 waves/CU, enabled by FULL-OVERLAY: P3 keeps p in registers (18 f16x4),
// barrier, then shp16 (256x304 = 77824B) overlays the ENTIRE blob (dead
// after P3). LDS = 77824 + shld 3072 = 80896 -> 2 blocks/CU.
// P1 is a kc-pair loop to cap live acc regs (~95 VGPR peak, cap 128).
// LDS: blob [0,77824) overlaid by shp16 after BARRIER A | shld [77824,80896).

#define TILE 256
#define NT   512
#define HID  128
#define OUTD 141
#define SRS  152     // halves per sample in shp16 (304 B rows)
#define BND  5.0f
#define T1   0.5413248546f   // ln(e-1): softplus(T1) = 1

typedef __bf16 bf16;
typedef _Float16 f16;
typedef __attribute__((ext_vector_type(8))) __bf16 bf16x8;
typedef __attribute__((ext_vector_type(8))) _Float16 f16x8;
typedef __attribute__((ext_vector_type(4))) _Float16 f16x4;
typedef __attribute__((ext_vector_type(2))) _Float16 f16x2;
typedef __attribute__((ext_vector_type(4))) float f32x4;

// fragment-index bases in the packed weight blob (fragment = 64 lanes x 16 B)
#define W3BASE 0         // 9 t3 x 4 kc = 36 tiles -> frags [0, 2304)
#define W1BASE 2304      // 8 tiles               -> frags [2304, 2816)
#define W2BASE 2816      // 8 m-tiles x 4 kc      -> frags [2816, 4864)
#define NFRAG  4864      // 77824 bytes total
#define B3P_OFF (NFRAG * 16)   // byte offset of b3p in d_ws

#define SHLD_OFF  77824
#define SMEM_BYTES 80896      // 2 blocks/CU (163840/80896 = 2.02)

// One thread per 8-elem A-fragment (W^T in A-layout: A[m=lane&15][k=lq*8+j]).
// k-permutation for W2/W3: feat = (kc*2+(j>>2))*16 + lq*4 + (j&3)  (f mapping,
// matches the in-lane D->B repack of the transposed chain — verified r11/r13).
__global__ void nsc_prepack(const float* __restrict__ W1, const float* __restrict__ W2,
                            const float* __restrict__ W3, const float* __restrict__ b3,
                            bf16* __restrict__ Wall, float* __restrict__ b3p) {
    int f = blockIdx.x * 256 + threadIdx.x;
    int lane = f & 63, lm = lane & 15, lq = lane >> 4;
    if (f < W1BASE) {                                // W3^T frags
        int tk = f >> 6, t3 = tk >> 2, kc = tk & 3;
        int col = t3 * 16 + lm;
        bf16x8 pk;
        #pragma unroll
        for (int j = 0; j < 8; ++j) {
            int feat = ((kc * 2 + (j >> 2)) << 4) + (lq << 2) + (j & 3);
            pk[j] = (col < OUTD) ? (bf16)W3[feat * OUTD + col] : (bf16)0.f;
        }
        *(bf16x8*)&Wall[(size_t)f * 8] = pk;
    } else if (f < W2BASE) {                         // W1^T frags (identity k, 7 feats)
        int t = (f - W1BASE) >> 6;
        int m = t * 16 + lm;
        bf16x8 pk;
        #pragma unroll
        for (int j = 0; j < 8; ++j) {
            int k = lq * 8 + j;
            pk[j] = (k < 7) ? (bf16)W1[k * HID + m] : (bf16)0.f;
        }
        *(bf16x8*)&Wall[(size_t)f * 8] = pk;
    } else if (f < NFRAG) {                          // W2^T frags
        int tk = (f - W2BASE) >> 6, t2 = tk >> 2, kc = tk & 3;
        int m = t2 * 16 + lm;
        bf16x8 pk;
        #pragma unroll
        for (int j = 0; j < 8; ++j) {
            int feat = ((kc * 2 + (j >> 2)) << 4) + (lq << 2) + (j & 3);
            pk[j] = (bf16)W2[feat * HID + m];
        }
        *(bf16x8*)&Wall[(size_t)f * 8] = pk;
    } else if (f < NFRAG + 144) {                    // b3 padded to 144
        int i = f - NFRAG;
        b3p[i] = (i < OUTD) ? b3[i] : 0.f;
    }
}

__global__ __launch_bounds__(NT, 4) void nsc_main(
    const float* __restrict__ x, const float* __restrict__ c,
    const bf16* __restrict__ Wall, const float* __restrict__ b1,
    const float* __restrict__ b2, const float* __restrict__ b3p,
    float* __restrict__ out_y, float* __restrict__ out_ld, int N)
{
    __shared__ __align__(16) char smem[SMEM_BYTES];
    bf16*  wlds  = (bf16*)smem;                 // staged blob (dead after P3)
    f16*   shp16 = (f16*)smem;                  // [256][SRS] OVERLAYS blob after BARRIER A
    float* shld  = (float*)(smem + SHLD_OFF);   // [256][3]

    const int tid  = threadIdx.x;
    const int g0   = blockIdx.x * TILE;
    const int lane = tid & 63;
    const int wv   = tid >> 6;        // 0..7: wave owns samples wv*32 .. wv*32+31
    const int lm   = lane & 15;
    const int lq   = lane >> 4;
    const int sbase = wv * 32;

    // ---- Input loads (2 sets/wave) first, overlap with staging ----
    float vin[2][8];
    #pragma unroll
    for (int set = 0; set < 2; ++set) {
        #pragma unroll
        for (int j = 0; j < 8; ++j) vin[set][j] = 0.f;
        int g = g0 + sbase + set * 16 + lm;
        if (lq == 0 && g < N) {
            vin[set][0] = x[g * 6 + 3]; vin[set][1] = x[g * 6 + 4];
            vin[set][2] = x[g * 6 + 5];
            vin[set][3] = c[g * 4];     vin[set][4] = c[g * 4 + 1];
            vin[set][5] = c[g * 4 + 2]; vin[set][6] = c[g * 4 + 3];
        }
    }

    // ---- Stage the 77824 B blob: 10 x (dwordx4 load + b128 LDS store) ----
    {
        const float4* src = (const float4*)Wall;
        float4* dst = (float4*)smem;
        #pragma unroll
        for (int j = 0; j < 10; ++j) {
            int idx = tid + j * NT;           // 0..4863 (last round tid<256)
            if (idx < NFRAG) dst[idx] = src[idx];
        }
    }
    __syncthreads();   // staging complete

    // ---- Build B1 input fragments ----
    bf16x8 inb[2];
    #pragma unroll
    for (int set = 0; set < 2; ++set) {
        bf16x8 t;
        #pragma unroll
        for (int j = 0; j < 8; ++j) t[j] = (bf16)vin[set][j];
        inb[set] = t;
    }

    // ---- Phase 1: h1^T = W1^T @ in^T + b1 (kc-pair loop, shared frags) ----
    bf16x8 h1B[2][4];
    #pragma unroll
    for (int kc = 0; kc < 4; ++kc) {
        bf16x8 wf0 = *(const bf16x8*)&wlds[(size_t)((W1BASE + (2 * kc) * 64 + lane)) * 8];
        bf16x8 wf1 = *(const bf16x8*)&wlds[(size_t)((W1BASE + (2 * kc + 1) * 64 + lane)) * 8];
        f32x4 b0 = *(const f32x4*)&b1[(2 * kc) * 16 + lq * 4];
        f32x4 b1v = *(const f32x4*)&b1[(2 * kc + 1) * 16 + lq * 4];
        f32x4 a0s0 = __builtin_amdgcn_mfma_f32_16x16x32_bf16(wf0, inb[0], b0, 0, 0, 0);
        f32x4 a0s1 = __builtin_amdgcn_mfma_f32_16x16x32_bf16(wf0, inb[1], b0, 0, 0, 0);
        f32x4 a1s0 = __builtin_amdgcn_mfma_f32_16x16x32_bf16(wf1, inb[0], b1v, 0, 0, 0);
        f32x4 a1s1 = __builtin_amdgcn_mfma_f32_16x16x32_bf16(wf1, inb[1], b1v, 0, 0, 0);
        // repack: slot (kc,j) <- relu(tile(kc*2+(j>>2)).reg[j&3])
        bf16x8 h0, h1;
        #pragma unroll
        for (int j = 0; j < 4; ++j) {
            h0[j]     = (bf16)fmaxf(a0s0[j], 0.f);
            h0[4 + j] = (bf16)fmaxf(a1s0[j], 0.f);
            h1[j]     = (bf16)fmaxf(a0s1[j], 0.f);
            h1[4 + j] = (bf16)fmaxf(a1s1[j], 0.f);
        }
        h1B[0][kc] = h0;
        h1B[1][kc] = h1;
    }

    // ---- Phase 2: h2^T = W2^T @ h1^T + b2 (shared frags, 2 sets) ----
    bf16x8 h2B[2][4];
    #pragma unroll
    for (int tp = 0; tp < 4; ++tp) {
        f32x4 acc[2][2];
        #pragma unroll
        for (int dt = 0; dt < 2; ++dt) {
            f32x4 bb = *(const f32x4*)&b2[(tp * 2 + dt) * 16 + lq * 4];
            acc[0][dt] = bb; acc[1][dt] = bb;
        }
        #pragma unroll
        for (int kc = 0; kc < 4; ++kc)
            #pragma unroll
            for (int dt = 0; dt < 2; ++dt) {
                bf16x8 wf = *(const bf16x8*)&wlds[(size_t)((W2BASE + ((tp * 2 + dt) * 4 + kc) * 64 + lane)) * 8];
                acc[0][dt] = __builtin_amdgcn_mfma_f32_16x16x32_bf16(wf, h1B[0][kc], acc[0][dt], 0, 0, 0);
                acc[1][dt] = __builtin_amdgcn_mfma_f32_16x16x32_bf16(wf, h1B[1][kc], acc[1][dt], 0, 0, 0);
            }
        #pragma unroll
        for (int set = 0; set < 2; ++set) {
            bf16x8 hb;
            #pragma unroll
            for (int j = 0; j < 8; ++j)
                hb[j] = (bf16)fmaxf(acc[set][j >> 2][j & 3], 0.f);
            h2B[set][tp] = hb;      // kc-group of next GEMM == tp (f mapping)
        }
    }

    // ---- Phase 3: p^T = W3^T @ h2^T + b3 -> REGISTERS (shared frags) ----
    f16x4 pk[2][9];
    #pragma unroll
    for (int t3 = 0; t3 < 9; ++t3) {
        f32x4 acc[2];
        {
            f32x4 bb = *(const f32x4*)&b3p[t3 * 16 + lq * 4];
            acc[0] = bb; acc[1] = bb;
        }
        #pragma unroll
        for (int kc = 0; kc < 4; ++kc) {
            bf16x8 wf = *(const bf16x8*)&wlds[(size_t)((W3BASE + (t3 * 4 + kc) * 64 + lane)) * 8];
            acc[0] = __builtin_amdgcn_mfma_f32_16x16x32_bf16(wf, h2B[0][kc], acc[0], 0, 0, 0);
            acc[1] = __builtin_amdgcn_mfma_f32_16x16x32_bf16(wf, h2B[1][kc], acc[1], 0, 0, 0);
        }
        #pragma unroll
        for (int set = 0; set < 2; ++set)
            pk[set][t3] = (f16x4){(f16)acc[set][0], (f16)acc[set][1],
                                  (f16)acc[set][2], (f16)acc[set][3]};
    }
    __syncthreads();   // BARRIER A: ALL blob reads done -> shp16 may overlay

    // ---- Scatter p registers to shp16 (overlays blob region) ----
    #pragma unroll
    for (int set = 0; set < 2; ++set) {
        int s = sbase + set * 16 + lm;
        #pragma unroll
        for (int t3 = 0; t3 < 9; ++t3) {
            int off = t3 * 16 + lq * 4;
            if (t3 < 8) {
                *(f16x4*)&shp16[s * SRS + off] = pk[set][t3];
            } else {
                if (lq < 3) *(f16x4*)&shp16[s * SRS + off] = pk[set][t3];
                else        shp16[s * SRS + 140] = pk[set][t3][0];   // col 140
            }
        }
    }
    __syncthreads();   // BARRIER B: scatters visible to all waves

    // ---- Phase 4: spline; 12 groups over 8 waves (grp = wv, then 8+wv for wv<4) ----
    #pragma unroll 1
    for (int rr = 0; rr < 2; ++rr) {
        if (rr == 1 && wv >= 4) break;
        const int grp = (rr == 0) ? wv : (8 + wv);
        const int d = grp >> 2;
        const int s = (grp & 3) * 64 + lane;
        const int g = g0 + s;
        if (g < N) {
            const f16* pr = &shp16[s * SRS];
            float w_[16], h_[16], dl[15];
            if (d == 0) {               // p[0..46]
                f16x8 A0 = *(const f16x8*)&pr[0],  A1 = *(const f16x8*)&pr[8];
                f16x8 A2 = *(const f16x8*)&pr[16], A3 = *(const f16x8*)&pr[24];
                f16x8 A4 = *(const f16x8*)&pr[32], A5 = *(const f16x8*)&pr[40];
                #pragma unroll
                for (int i = 0; i < 8; ++i) {
                    w_[i] = (float)A0[i]; w_[8 + i] = (float)A1[i];
                    h_[i] = (float)A2[i]; h_[8 + i] = (float)A3[i];
                    dl[i] = (float)A4[i];
                }
                #pragma unroll
                for (int i = 0; i < 7; ++i) dl[8 + i] = (float)A5[i];
            } else if (d == 1) {        // p[47..93]
                float a47 = (float)pr[47];
                f16x8 A0 = *(const f16x8*)&pr[48], A1 = *(const f16x8*)&pr[56];
                f16x8 A2 = *(const f16x8*)&pr[64], A3 = *(const f16x8*)&pr[72];
                f16x8 A4 = *(const f16x8*)&pr[80], A5 = *(const f16x8*)&pr[88];
                w_[0] = a47;
                #pragma unroll
                for (int i = 0; i < 8; ++i) w_[1 + i] = (float)A0[i];
                #pragma unroll
                for (int i = 0; i < 7; ++i) w_[9 + i] = (float)A1[i];
                h_[0] = (float)A1[7];
                #pragma unroll
                for (int i = 0; i < 8; ++i) h_[1 + i] = (float)A2[i];
                #pragma unroll
                for (int i = 0; i < 7; ++i) h_[9 + i] = (float)A3[i];
                dl[0] = (float)A3[7];
                #pragma unroll
                for (int i = 0; i < 8; ++i) dl[1 + i] = (float)A4[i];
                #pragma unroll
                for (int i = 0; i < 6; ++i) dl[9 + i] = (float)A5[i];
            } else {                    // p[94..140]
                f16x2 B  = *(const f16x2*)&pr[94];
                f16x8 C0 = *(const f16x8*)&pr[96];
                f16x8 C1 = *(const f16x8*)&pr[104];
                f16x8 C2 = *(const f16x8*)&pr[112];
                f16x8 C3 = *(const f16x8*)&pr[120];
                f16x8 C4 = *(const f16x8*)&pr[128];
                f16x8 E  = *(const f16x8*)&pr[136];
                w_[0] = (float)B[0]; w_[1] = (float)B[1];
                #pragma unroll
                for (int i = 0; i < 8; ++i) w_[2 + i] = (float)C0[i];
                #pragma unroll
                for (int i = 0; i < 6; ++i) w_[10 + i] = (float)C1[i];
                h_[0] = (float)C1[6]; h_[1] = (float)C1[7];
                #pragma unroll
                for (int i = 0; i < 8; ++i) h_[2 + i] = (float)C2[i];
                #pragma unroll
                for (int i = 0; i < 6; ++i) h_[10 + i] = (float)C3[i];
                dl[0] = (float)C3[6]; dl[1] = (float)C3[7];
                #pragma unroll
                for (int i = 0; i < 8; ++i) dl[2 + i] = (float)C4[i];
                #pragma unroll
                for (int i = 0; i < 5; ++i) dl[10 + i] = (float)E[i];
            }

            // softmax without max-subtract: logits are O(1)
            float sw = 0.f, sh = 0.f;
            #pragma unroll
            for (int i = 0; i < 16; ++i) { w_[i] = __expf(w_[i]); sw += w_[i]; }
            #pragma unroll
            for (int i = 0; i < 16; ++i) { h_[i] = __expf(h_[i]); sh += h_[i]; }
            float cwn = 10.f * __builtin_amdgcn_rcpf(sw);
            float chn = 10.f * __builtin_amdgcn_rcpf(sh);
            #pragma unroll
            for (int i = 0; i < 16; ++i) { w_[i] *= cwn; h_[i] *= chn; }

            float xv = x[g * 6 + d];
            bool oob = (xv <= -BND) || (xv >= BND);
            float xm = oob ? -BND : xv;

            // bin scan; softplus deferred to the 2 selected derivs
            float cumx = -BND + w_[0], cumy = -BND + h_[0];
            float xk_b = -BND, yk_b = -BND;
            float wk = w_[0], hk = h_[0];
            float d0l = T1, d1l = dl[0];
            #pragma unroll
            for (int i = 1; i < 16; ++i) {
                bool ge = (xm >= cumx);
                if (ge) {
                    xk_b = cumx; yk_b = cumy;
                    wk = w_[i]; hk = h_[i];
                    d0l = dl[i - 1];
                    d1l = (i < 15) ? dl[i] : T1;
                }
                cumx += w_[i]; cumy += h_[i];
            }
            float d0 = (d0l > 15.f) ? d0l : __logf(1.f + __expf(d0l));
            float d1 = (d1l > 15.f) ? d1l : __logf(1.f + __expf(d1l));

            float rwk = __builtin_amdgcn_rcpf(wk);
            float sk = hk * rwk;
            float relx = (xm - xk_b) * rwk;
            relx = fminf(fmaxf(relx, 0.f), 1.f);
            float r1 = relx * (1.f - relx);
            float den = sk + (d1 + d0 - 2.f * sk) * r1;
            float iden = __builtin_amdgcn_rcpf(den);
            float num = hk * (sk * relx * relx + d0 * r1);
            float y = yk_b + num * iden;
            float omr = 1.f - relx;
            float arg = d1 * relx * relx + 2.f * sk * r1 + d0 * omr * omr;
            float ratio = sk * iden;
            float ld = __logf(ratio * ratio * arg);   // 2log(sk)+log(arg)-2log(den)
            if (oob) { y = xv; ld = 0.f; }

            out_y[g * 6 + d] = y;
            out_y[g * 6 + 3 + d] = x[g * 6 + 3 + d];  // upper pass-through (fp32)
            shld[s * 3 + d] = ld;
        }
    }
    __syncthreads();   // BARRIER C

    // ---- Phase 5: reduce log-det over the 3 dims ----
    if (tid < TILE) {
        int g = g0 + tid;
        if (g < N)
            out_ld[g] = shld[tid * 3] + shld[tid * 3 + 1] + shld[tid * 3 + 2];
    }
}

extern "C" void kernel_launch(void* const* d_in, const int* in_sizes, int n_in,
                              void* d_out, int out_size, void* d_ws, size_t ws_size,
                              hipStream_t stream) {
    const float* x  = (const float*)d_in[0];
    const float* c  = (const float*)d_in[1];
    const float* W1 = (const float*)d_in[2];
    const float* b1 = (const float*)d_in[3];
    const float* W2 = (const float*)d_in[4];
    const float* b2 = (const float*)d_in[5];
    const float* W3 = (const float*)d_in[6];
    const float* b3 = (const float*)d_in[7];

    const int N = in_sizes[0] / 6;              // 500000
    float* out_y  = (float*)d_out;
    float* out_ld = (float*)d_out + (size_t)N * 6;

    bf16*  Wall = (bf16*)d_ws;                          // 77824 B blob
    float* b3p  = (float*)((char*)d_ws + B3P_OFF);      // 576 B

    int nthreads = NFRAG + 144;                 // 5008
    nsc_prepack<<<(nthreads + 255) / 256, 256, 0, stream>>>(W1, W2, W3, b3,
                                                            Wall, b3p);

    int nblocks = (N + TILE - 1) / TILE;        // 1954
    nsc_main<<<nblocks, NT, 0, stream>>>(x, c, Wall, b1, b2, b3p,
                                         out_y, out_ld, N);
}

// Round 16
// 132.215 us; speedup vs baseline: 1.2582x; 1.0110x over previous
//
#include <hip/hip_runtime.h>
#include <math.h>

// NeuralSplineCoupling: y[:, :3] = RQS(x[:, :3]; params = MLP([x[:,3:], c]))
//                       y[:, 3:] = x[:, 3:],  log_det = sum over 3 dims
// N = 500000, X_DIM=6, C_DIM=4, HID=128, KNOTS=16, SPLINE_DIM=47, OUT_DIM=141
//
// Round 28 == Round 26 resubmit (GPU acquisition timed out twice; unmeasured).
// r25 (MEASURED 62.4us main; frag-sharing 2 sets/wave @ 16 waves/CU
// via full blob<->shp16 overlay; MfmaUtil 24.8, VALU 49.6) + phase-4 cuts:
//  (1) PADDED P-LAYOUT VIA PREPACK: W3 cols + b3 permuted to c' = 48*dim + j
//      (141 -> 144 cols; j=47 slots are zero-weight dead pads). P3 scatter is
//      now a UNIFORM aligned f16x4 store (t3 0..8, no tail/crossing cases);
//      phase-4 gather is ONE branchless path: 6 aligned f16x8 loads at
//      shp16[s*SRS + 48*d] (w_=0..15, h_=16..31, dl=32..46). Kills the 3-way
//      divergent gather (d=1/d=2 scalar-assembly branches).
//  (2) DEFERRED SOFTMAX NORM: bin scan runs in unnormalized space
//      (txm = (xm+B)*sw*0.1 vs raw cumsum); only the 4 selected values get
//      normalized afterwards (~25 VALU/body saved). Equivalent modulo FP
//      rounding order.
//  (3) shld folded into shp16 row pad (halves 144..149; reads cover 0..143
//      only -> no byte overlap). SMEM 80896 -> 77824 (still 2 blocks/CU).
// LDS: blob [0,77824) overlaid by shp16[256][SRS] after BARRIER A.

#define TILE 256
#define NT   512
#define HID  128
#define OUTD 141
#define SRS  152     // halves per sample (304 B rows): 3*48 params + 2 ld-pad
#define BND  5.0f
#define T1   0.5413248546f   // ln(e-1): softplus(T1) = 1

typedef __bf16 bf16;
typedef _Float16 f16;
typedef __attribute__((ext_vector_type(8))) __bf16 bf16x8;
typedef __attribute__((ext_vector_type(8))) _Float16 f16x8;
typedef __attribute__((ext_vector_type(4))) _Float16 f16x4;
typedef __attribute__((ext_vector_type(2))) _Float16 f16x2;
typedef __attribute__((ext_vector_type(4))) float f32x4;

// fragment-index bases in the packed weight blob (fragment = 64 lanes x 16 B)
#define W3BASE 0         // 9 t3 x 4 kc = 36 tiles -> frags [0, 2304)
#define W1BASE 2304      // 8 tiles               -> frags [2304, 2816)
#define W2BASE 2816      // 8 m-tiles x 4 kc      -> frags [2816, 4864)
#define NFRAG  4864      // 77824 bytes total
#define B3P_OFF (NFRAG * 16)   // byte offset of b3p in d_ws

#define SMEM_BYTES 77824      // 2 blocks/CU (163840/77824 = 2.1)

// One thread per 8-elem A-fragment (W^T in A-layout: A[m=lane&15][k=lq*8+j]).
// k-permutation for W2/W3: feat = (kc*2+(j>>2))*16 + lq*4 + (j&3)  (f mapping,
// matches the in-lane D->B repack of the transposed chain — verified r11/r13).
// W3 COLUMN PERMUTATION (r26): output col' = t3*16+lm in [0,144);
// dim dq = col'/48, j = col'%48; real col = 47*dq + j (j==47 -> zero pad).
__global__ void nsc_prepack(const float* __restrict__ W1, const float* __restrict__ W2,
                            const float* __restrict__ W3, const float* __restrict__ b3,
                            bf16* __restrict__ Wall, float* __restrict__ b3p) {
    int f = blockIdx.x * 256 + threadIdx.x;
    int lane = f & 63, lm = lane & 15, lq = lane >> 4;
    if (f < W1BASE) {                                // W3^T frags (padded cols)
        int tk = f >> 6, t3 = tk >> 2, kc = tk & 3;
        int colp = t3 * 16 + lm;                     // padded col' in [0,144)
        int dq = colp / 48;
        int jj = colp - dq * 48;
        int col = 47 * dq + jj;                      // real col (valid if jj<47)
        bf16x8 pk;
        #pragma unroll
        for (int j = 0; j < 8; ++j) {
            int feat = ((kc * 2 + (j >> 2)) << 4) + (lq << 2) + (j & 3);
            pk[j] = (jj < 47) ? (bf16)W3[feat * OUTD + col] : (bf16)0.f;
        }
        *(bf16x8*)&Wall[(size_t)f * 8] = pk;
    } else if (f < W2BASE) {                         // W1^T frags (identity k, 7 feats)
        int t = (f - W1BASE) >> 6;
        int m = t * 16 + lm;
        bf16x8 pk;
        #pragma unroll
        for (int j = 0; j < 8; ++j) {
            int k = lq * 8 + j;
            pk[j] = (k < 7) ? (bf16)W1[k * HID + m] : (bf16)0.f;
        }
        *(bf16x8*)&Wall[(size_t)f * 8] = pk;
    } else if (f < NFRAG) {                          // W2^T frags
        int tk = (f - W2BASE) >> 6, t2 = tk >> 2, kc = tk & 3;
        int m = t2 * 16 + lm;
        bf16x8 pk;
        #pragma unroll
        for (int j = 0; j < 8; ++j) {
            int feat = ((kc * 2 + (j >> 2)) << 4) + (lq << 2) + (j & 3);
            pk[j] = (bf16)W2[feat * HID + m];
        }
        *(bf16x8*)&Wall[(size_t)f * 8] = pk;
    } else if (f < NFRAG + 144) {                    // b3 permuted+padded to 144
        int i = f - NFRAG;
        int dq = i / 48;
        int jj = i - dq * 48;
        b3p[i] = (jj < 47) ? b3[47 * dq + jj] : 0.f;
    }
}

__global__ __launch_bounds__(NT, 4) void nsc_main(
    const float* __restrict__ x, const float* __restrict__ c,
    const bf16* __restrict__ Wall, const float* __restrict__ b1,
    const float* __restrict__ b2, const float* __restrict__ b3p,
    float* __restrict__ out_y, float* __restrict__ out_ld, int N)
{
    __shared__ __align__(16) char smem[SMEM_BYTES];
    bf16*  wlds  = (bf16*)smem;                 // staged blob (dead after P3)
    f16*   shp16 = (f16*)smem;                  // [256][SRS] OVERLAYS blob after BARRIER A

    const int tid  = threadIdx.x;
    const int g0   = blockIdx.x * TILE;
    const int lane = tid & 63;
    const int wv   = tid >> 6;        // 0..7: wave owns samples wv*32 .. wv*32+31
    const int lm   = lane & 15;
    const int lq   = lane >> 4;
    const int sbase = wv * 32;

    // ---- Input loads (2 sets/wave) first, overlap with staging ----
    float vin[2][8];
    #pragma unroll
    for (int set = 0; set < 2; ++set) {
        #pragma unroll
        for (int j = 0; j < 8; ++j) vin[set][j] = 0.f;
        int g = g0 + sbase + set * 16 + lm;
        if (lq == 0 && g < N) {
            vin[set][0] = x[g * 6 + 3]; vin[set][1] = x[g * 6 + 4];
            vin[set][2] = x[g * 6 + 5];
            vin[set][3] = c[g * 4];     vin[set][4] = c[g * 4 + 1];
            vin[set][5] = c[g * 4 + 2]; vin[set][6] = c[g * 4 + 3];
        }
    }

    // ---- Stage the 77824 B blob: 10 x (dwordx4 load + b128 LDS store) ----
    {
        const float4* src = (const float4*)Wall;
        float4* dst = (float4*)smem;
        #pragma unroll
        for (int j = 0; j < 10; ++j) {
            int idx = tid + j * NT;           // 0..4863 (last round tid<256)
            if (idx < NFRAG) dst[idx] = src[idx];
        }
    }
    __syncthreads();   // staging complete

    // ---- Build B1 input fragments ----
    bf16x8 inb[2];
    #pragma unroll
    for (int set = 0; set < 2; ++set) {
        bf16x8 t;
        #pragma unroll
        for (int j = 0; j < 8; ++j) t[j] = (bf16)vin[set][j];
        inb[set] = t;
    }

    // ---- Phase 1: h1^T = W1^T @ in^T + b1 (kc-pair loop, shared frags) ----
    bf16x8 h1B[2][4];
    #pragma unroll
    for (int kc = 0; kc < 4; ++kc) {
        bf16x8 wf0 = *(const bf16x8*)&wlds[(size_t)((W1BASE + (2 * kc) * 64 + lane)) * 8];
        bf16x8 wf1 = *(const bf16x8*)&wlds[(size_t)((W1BASE + (2 * kc + 1) * 64 + lane)) * 8];
        f32x4 b0 = *(const f32x4*)&b1[(2 * kc) * 16 + lq * 4];
        f32x4 b1v = *(const f32x4*)&b1[(2 * kc + 1) * 16 + lq * 4];
        f32x4 a0s0 = __builtin_amdgcn_mfma_f32_16x16x32_bf16(wf0, inb[0], b0, 0, 0, 0);
        f32x4 a0s1 = __builtin_amdgcn_mfma_f32_16x16x32_bf16(wf0, inb[1], b0, 0, 0, 0);
        f32x4 a1s0 = __builtin_amdgcn_mfma_f32_16x16x32_bf16(wf1, inb[0], b1v, 0, 0, 0);
        f32x4 a1s1 = __builtin_amdgcn_mfma_f32_16x16x32_bf16(wf1, inb[1], b1v, 0, 0, 0);
        // repack: slot (kc,j) <- relu(tile(kc*2+(j>>2)).reg[j&3])
        bf16x8 h0, h1;
        #pragma unroll
        for (int j = 0; j < 4; ++j) {
            h0[j]     = (bf16)fmaxf(a0s0[j], 0.f);
            h0[4 + j] = (bf16)fmaxf(a1s0[j], 0.f);
            h1[j]     = (bf16)fmaxf(a0s1[j], 0.f);
            h1[4 + j] = (bf16)fmaxf(a1s1[j], 0.f);
        }
        h1B[0][kc] = h0;
        h1B[1][kc] = h1;
    }

    // ---- Phase 2: h2^T = W2^T @ h1^T + b2 (shared frags, 2 sets) ----
    bf16x8 h2B[2][4];
    #pragma unroll
    for (int tp = 0; tp < 4; ++tp) {
        f32x4 acc[2][2];
        #pragma unroll
        for (int dt = 0; dt < 2; ++dt) {
            f32x4 bb = *(const f32x4*)&b2[(tp * 2 + dt) * 16 + lq * 4];
            acc[0][dt] = bb; acc[1][dt] = bb;
        }
        #pragma unroll
        for (int kc = 0; kc < 4; ++kc)
            #pragma unroll
            for (int dt = 0; dt < 2; ++dt) {
                bf16x8 wf = *(const bf16x8*)&wlds[(size_t)((W2BASE + ((tp * 2 + dt) * 4 + kc) * 64 + lane)) * 8];
                acc[0][dt] = __builtin_amdgcn_mfma_f32_16x16x32_bf16(wf, h1B[0][kc], acc[0][dt], 0, 0, 0);
                acc[1][dt] = __builtin_amdgcn_mfma_f32_16x16x32_bf16(wf, h1B[1][kc], acc[1][dt], 0, 0, 0);
            }
        #pragma unroll
        for (int set = 0; set < 2; ++set) {
            bf16x8 hb;
            #pragma unroll
            for (int j = 0; j < 8; ++j)
                hb[j] = (bf16)fmaxf(acc[set][j >> 2][j & 3], 0.f);
            h2B[set][tp] = hb;      // kc-group of next GEMM == tp (f mapping)
        }
    }

    // ---- Phase 3: p^T = W3^T @ h2^T + b3 -> REGISTERS (shared frags) ----
    f16x4 pk[2][9];
    #pragma unroll
    for (int t3 = 0; t3 < 9; ++t3) {
        f32x4 acc[2];
        {
            f32x4 bb = *(const f32x4*)&b3p[t3 * 16 + lq * 4];
            acc[0] = bb; acc[1] = bb;
        }
        #pragma unroll
        for (int kc = 0; kc < 4; ++kc) {
            bf16x8 wf = *(const bf16x8*)&wlds[(size_t)((W3BASE + (t3 * 4 + kc) * 64 + lane)) * 8];
            acc[0] = __builtin_amdgcn_mfma_f32_16x16x32_bf16(wf, h2B[0][kc], acc[0], 0, 0, 0);
            acc[1] = __builtin_amdgcn_mfma_f32_16x16x32_bf16(wf, h2B[1][kc], acc[1], 0, 0, 0);
        }
        #pragma unroll
        for (int set = 0; set < 2; ++set)
            pk[set][t3] = (f16x4){(f16)acc[set][0], (f16)acc[set][1],
                                  (f16)acc[set][2], (f16)acc[set][3]};
    }
    __syncthreads();   // BARRIER A: ALL blob reads done -> shp16 may overlay

    // ---- Scatter p registers to shp16 (UNIFORM: padded layout) ----
    #pragma unroll
    for (int set = 0; set < 2; ++set) {
        int s = sbase + set * 16 + lm;
        #pragma unroll
        for (int t3 = 0; t3 < 9; ++t3)
            *(f16x4*)&shp16[s * SRS + t3 * 16 + lq * 4] = pk[set][t3];
    }
    __syncthreads();   // BARRIER B: scatters visible to all waves

    // ---- Phase 4: spline; 12 groups over 8 waves (grp = wv, then 8+wv for wv<4) ----
    #pragma unroll 1
    for (int rr = 0; rr < 2; ++rr) {
        if (rr == 1 && wv >= 4) break;
        const int grp = (rr == 0) ? wv : (8 + wv);
        const int d = grp >> 2;
        const int s = (grp & 3) * 64 + lane;
        const int g = g0 + s;
        if (g < N) {
            // ONE branchless gather: dim d at halves 48*d (16B aligned)
            const f16* pr = &shp16[s * SRS + 48 * d];
            float w_[16], h_[16], dl[15];
            {
                f16x8 A0 = *(const f16x8*)&pr[0],  A1 = *(const f16x8*)&pr[8];
                f16x8 A2 = *(const f16x8*)&pr[16], A3 = *(const f16x8*)&pr[24];
                f16x8 A4 = *(const f16x8*)&pr[32], A5 = *(const f16x8*)&pr[40];
                #pragma unroll
                for (int i = 0; i < 8; ++i) {
                    w_[i] = (float)A0[i]; w_[8 + i] = (float)A1[i];
                    h_[i] = (float)A2[i]; h_[8 + i] = (float)A3[i];
                    dl[i] = (float)A4[i];
                }
                #pragma unroll
                for (int i = 0; i < 7; ++i) dl[8 + i] = (float)A5[i];
            }

            // exp (UNNORMALIZED; logits are O(1), no max-subtract needed)
            float sw = 0.f, sh = 0.f;
            #pragma unroll
            for (int i = 0; i < 16; ++i) { w_[i] = __expf(w_[i]); sw += w_[i]; }
            #pragma unroll
            for (int i = 0; i < 16; ++i) { h_[i] = __expf(h_[i]); sh += h_[i]; }
            float cwn = 10.f * __builtin_amdgcn_rcpf(sw);
            float chn = 10.f * __builtin_amdgcn_rcpf(sh);

            float xv = x[g * 6 + d];
            bool oob = (xv <= -BND) || (xv >= BND);
            float xm = oob ? -BND : xv;

            // DEFERRED-NORM bin scan: xm >= -B + cwn*prefix  <=>  txm >= prefix
            float txm = (xm + BND) * sw * 0.1f;
            float cum_u = w_[0], cumy_u = h_[0];
            float px_u = 0.f, py_u = 0.f;
            float wk_u = w_[0], hk_u = h_[0];
            float d0l = T1, d1l = dl[0];
            #pragma unroll
            for (int i = 1; i < 16; ++i) {
                bool ge = (txm >= cum_u);
                if (ge) {
                    px_u = cum_u; py_u = cumy_u;
                    wk_u = w_[i]; hk_u = h_[i];
                    d0l = dl[i - 1];
                    d1l = (i < 15) ? dl[i] : T1;
                }
                cum_u += w_[i]; cumy_u += h_[i];
            }
            // normalize only the selected values
            float xk_b = -BND + cwn * px_u;
            float yk_b = -BND + chn * py_u;
            float wk = cwn * wk_u;
            float hk = chn * hk_u;

            float d0 = (d0l > 15.f) ? d0l : __logf(1.f + __expf(d0l));
            float d1 = (d1l > 15.f) ? d1l : __logf(1.f + __expf(d1l));

            float rwk = __builtin_amdgcn_rcpf(wk);
            float sk = hk * rwk;
            float relx = (xm - xk_b) * rwk;
            relx = fminf(fmaxf(relx, 0.f), 1.f);
            float r1 = relx * (1.f - relx);
            float den = sk + (d1 + d0 - 2.f * sk) * r1;
            float iden = __builtin_amdgcn_rcpf(den);
            float num = hk * (sk * relx * relx + d0 * r1);
            float y = yk_b + num * iden;
            float omr = 1.f - relx;
            float arg = d1 * relx * relx + 2.f * sk * r1 + d0 * omr * omr;
            float ratio = sk * iden;
            float ld = __logf(ratio * ratio * arg);   // 2log(sk)+log(arg)-2log(den)
            if (oob) { y = xv; ld = 0.f; }

            out_y[g * 6 + d] = y;
            out_y[g * 6 + 3 + d] = x[g * 6 + 3 + d];  // upper pass-through (fp32)
            // ld into row pad (halves 144..149; readers only touch 0..143)
            float* lp = (float*)&shp16[s * SRS + 144];
            lp[d] = ld;
        }
    }
    __syncthreads();   // BARRIER C

    // ---- Phase 5: reduce log-det over the 3 dims (from row pads) ----
    if (tid < TILE) {
        int g = g0 + tid;
        if (g < N) {
            const float* lp = (const float*)&shp16[tid * SRS + 144];
            out_ld[g] = lp[0] + lp[1] + lp[2];
        }
    }
}

extern "C" void kernel_launch(void* const* d_in, const int* in_sizes, int n_in,
                              void* d_out, int out_size, void* d_ws, size_t ws_size,
                              hipStream_t stream) {
    const float* x  = (const float*)d_in[0];
    const float* c  = (const float*)d_in[1];
    const float* W1 = (const float*)d_in[2];
    const float* b1 = (const float*)d_in[3];
    const float* W2 = (const float*)d_in[4];
    const float* b2 = (const float*)d_in[5];
    const float* W3 = (const float*)d_in[6];
    const float* b3 = (const float*)d_in[7];

    const int N = in_sizes[0] / 6;              // 500000
    float* out_y  = (float*)d_out;
    float* out_ld = (float*)d_out + (size_t)N * 6;

    bf16*  Wall = (bf16*)d_ws;                          // 77824 B blob
    float* b3p  = (float*)((char*)d_ws + B3P_OFF);      // 576 B (144 floats)

    int nthreads = NFRAG + 144;                 // 5008
    nsc_prepack<<<(nthreads + 255) / 256, 256, 0, stream>>>(W1, W2, W3, b3,
                                                            Wall, b3p);

    int nblocks = (N + TILE - 1) / TILE;        // 1954
    nsc_main<<<nblocks, NT, 0, stream>>>(x, c, Wall, b1, b2, b3p,
                                         out_y, out_ld, N);
}